// Round 5
// baseline (23564.989 us; speedup 1.0000x reference)
//
#include <hip/hip_runtime.h>

#define S_LEN 8192
#define KREL 8
#define WPD 64   // workgroups per direction; each owns 512/WPD = 8 h-columns

typedef float f4 __attribute__((ext_vector_type(4)));

__device__ __forceinline__ float sigmf(float x) { return 1.0f / (1.0f + __expf(-x)); }
__device__ __forceinline__ float tanhfast(float x) { return 1.0f - 2.0f / (__expf(2.0f * x) + 1.0f); }

// ---------------- mask canonicalization (R2-verified) ----------------
__global__ void k_maskcvt(const unsigned char* __restrict__ src,
                          unsigned char* __restrict__ dst, int n)
{
  const unsigned int* w = (const unsigned int*)src;
  __shared__ int s_i32, s_f32;
  if (threadIdx.x == 0) { s_i32 = 1; s_f32 = 1; }
  __syncthreads();
  int i32ok = 1, f32ok = 1;
  for (int i = threadIdx.x; i < 1024; i += blockDim.x) {
    const unsigned int v = w[i];
    if (v != 0u && v != 1u) i32ok = 0;
    if (v != 0u && v != 0x3F800000u) f32ok = 0;
  }
  if (!i32ok) atomicAnd(&s_i32, 0);
  if (!f32ok) atomicAnd(&s_f32, 0);
  __syncthreads();
  const int wide = (s_i32 || s_f32);
  for (int i = blockIdx.x * blockDim.x + threadIdx.x; i < n; i += gridDim.x * blockDim.x)
    dst[i] = wide ? (w[i] ? 1 : 0) : (src[i] ? 1 : 0);
}

// ---------------- parallel precompute (R2-verified) ----------------
__global__ __launch_bounds__(256)
void k_gemm(const float* __restrict__ X, const float* __restrict__ Wioux,
            const float* __restrict__ Wlx, const float* __restrict__ bioux,
            const float* __restrict__ biouh, const float* __restrict__ blx,
            const float* __restrict__ blh, float* __restrict__ P)
{
  __shared__ float As[16][64];
  __shared__ float Bs[16][64];
  const int t0 = blockIdx.x * 64;
  const int r0 = blockIdx.y * 64;
  const int tid = threadIdx.x;
  const int tx = tid & 15, ty = tid >> 4;
  const int si = tid >> 2, sk = (tid & 3) << 2;
  const int rB = r0 + si;
  const float* brow = (rB < 2560) ? (Wioux + (size_t)rB * 512)
                                  : (Wlx + (size_t)(rB - 2560) * 512);
  const float* arow = X + (size_t)(t0 + si) * 512;
  float acc[4][4] = {};
  for (int k0 = 0; k0 < 512; k0 += 16) {
    const float4 av = *(const float4*)(arow + k0 + sk);
    const float4 bv = *(const float4*)(brow + k0 + sk);
    __syncthreads();
    As[sk + 0][si] = av.x; As[sk + 1][si] = av.y; As[sk + 2][si] = av.z; As[sk + 3][si] = av.w;
    Bs[sk + 0][si] = bv.x; Bs[sk + 1][si] = bv.y; Bs[sk + 2][si] = bv.z; Bs[sk + 3][si] = bv.w;
    __syncthreads();
#pragma unroll
    for (int kk = 0; kk < 16; ++kk) {
      const float4 a = *(const float4*)&As[kk][ty * 4];
      const float4 b = *(const float4*)&Bs[kk][tx * 4];
      acc[0][0] += a.x * b.x; acc[0][1] += a.x * b.y; acc[0][2] += a.x * b.z; acc[0][3] += a.x * b.w;
      acc[1][0] += a.y * b.x; acc[1][1] += a.y * b.y; acc[1][2] += a.y * b.z; acc[1][3] += a.y * b.w;
      acc[2][0] += a.z * b.x; acc[2][1] += a.z * b.y; acc[2][2] += a.z * b.z; acc[2][3] += a.z * b.w;
      acc[3][0] += a.w * b.x; acc[3][1] += a.w * b.y; acc[3][2] += a.w * b.z; acc[3][3] += a.w * b.w;
    }
  }
#pragma unroll
  for (int i = 0; i < 4; ++i) {
    const int t = t0 + ty * 4 + i;
#pragma unroll
    for (int j = 0; j < 4; ++j) {
      const int r = r0 + tx * 4 + j;
      const float bias = (r < 2560) ? (bioux[r] + biouh[r]) : (blx[r - 2560] + blh[r - 2560]);
      P[(size_t)t * 3072 + r] = acc[i][j] + bias;
    }
  }
}

// ---------------- persistent recurrent kernel ----------------
// v3: every latency hidden under the packet poll.
//  - 24 weight dwordx4 loads issued via inline asm at loop TOP (pre-poll);
//    asm-defined values can't be rematerialized/sunk. Poll's vmcnt(0) covers them.
//  - indices prefetched 2 steps ahead -> end-of-step gathers are 1-deep chains.
//  - all gather patches at use time from carried regs:
//      Hg: jj==prevt -> hprev
//      Gg: jj==prevt -> g ; jj==prevt2 -> gprev
//    (rows older than prevt2 crossed >=1 vmcnt(0) drain before their gather.)
//  - sm computed identically on ALL 32 lanes (no lane<8 zeroing).
__global__ __launch_bounds__(256, 1)
void k_rec(const float* __restrict__ Wiouh, const float* __restrict__ Wlh,
           const float* __restrict__ P, const float* __restrict__ lb,
           const int* __restrict__ rel_fw, const int* __restrict__ dep_fw,
           const unsigned char* __restrict__ mask_fw,
           const int* __restrict__ rel_bw, const int* __restrict__ dep_bw,
           const unsigned char* __restrict__ mask_bw,
           float* __restrict__ Gfw, float* __restrict__ Gbw,
           unsigned long long* rec, float* __restrict__ out)
{
  const int wg  = blockIdx.x;
  const int dir = wg / WPD;
  const int w   = wg % WPD;
  const int tid = threadIdx.x;
  const int grp = tid >> 5;            // 8 column-groups per WG
  const int lane = tid & 31;           // 32 lanes per column
  const int kl = lane & 7;             // owned relative slot (octets duplicate)
  const int m = w * 8 + grp;           // owned h-column
  const int dircol = dir * 512;
  const int* rel = dir ? rel_bw : rel_fw;
  const int* dep = dir ? dep_bw : dep_fw;
  const unsigned char* msk = dir ? mask_bw : mask_fw;
  float* Gbuf = dir ? Gbw : Gfw;

  // per-row weight base pointers (thread-fixed): row start + lane*4
  const float* wrow[6];
#pragma unroll
  for (int rg = 0; rg < 5; ++rg) wrow[rg] = Wiouh + (size_t)(rg * 512 + m) * 512 + lane * 4;
  wrow[5] = Wlh + (size_t)m * 512 + lane * 4;

  __shared__ float hs[2][512];
  hs[0][tid] = 0.0f; hs[0][tid + 256] = 0.0f;

  float cstate = 0.0f, hprev = 0.0f, gprev = 0.0f;

  // ---- prologue: step-0 gathers (dead: first step fully masked) + step-1 indices ----
  int jjU, mkU, jjN, mkN, depN;
  float Hg, Gg, LBg;
  float p0, p1, p2, p3, p4, p5;
  {
    const int t0 = dir ? (S_LEN - 1) : 0;
    const int t1 = dir ? (S_LEN - 2) : 1;
    jjU = rel[t0 * KREL + kl]; mkU = (int)msk[t0 * KREL + kl];
    Hg  = out[(size_t)jjU * 1024 + dircol + m];
    Gg  = Gbuf[(size_t)jjU * 512 + m];
    LBg = lb[(size_t)dep[t0 * KREL + kl] * 512 + m];
    const float* prow = P + (size_t)t0 * 3072;
    p0 = prow[m];        p1 = prow[512 + m];  p2 = prow[1024 + m];
    p3 = prow[1536 + m]; p4 = prow[2048 + m]; p5 = prow[2560 + m];
    jjN = rel[t1 * KREL + kl]; mkN = (int)msk[t1 * KREL + kl]; depN = dep[t1 * KREL + kl];
  }
  __syncthreads();

#pragma unroll 1
  for (int s = 0; s < S_LEN; ++s) {
    const int t = dir ? (S_LEN - 1 - s) : s;
    const int tn = dir ? (t - 1) : (t + 1);
    const int prevt  = dir ? (t + 1) : (t - 1);   // fires only when s>0 (else no jj match)
    const int prevt2 = dir ? (t + 2) : (t - 2);

    // ---- (A) issue weight loads NOW; latency hides under the poll ----
    f4 wf[6][4];
#pragma unroll
    for (int rg = 0; rg < 6; ++rg)
      asm volatile("global_load_dwordx4 %0, %4, off\n\t"
                   "global_load_dwordx4 %1, %4, off offset:512\n\t"
                   "global_load_dwordx4 %2, %4, off offset:1024\n\t"
                   "global_load_dwordx4 %3, %4, off offset:1536"
                   : "=v"(wf[rg][0]), "=v"(wf[rg][1]), "=v"(wf[rg][2]), "=v"(wf[rg][3])
                   : "v"(wrow[rg]) : "memory");

    // ---- (B) poll packets, broadcast h through LDS ----
    if (s > 0) {
      const int pb = (((s - 1) & 1) * 2 + dir) * 512;
      unsigned long long v0 = __hip_atomic_load(rec + pb + tid,       __ATOMIC_RELAXED, __HIP_MEMORY_SCOPE_AGENT);
      unsigned long long v1 = __hip_atomic_load(rec + pb + tid + 256, __ATOMIC_RELAXED, __HIP_MEMORY_SCOPE_AGENT);
      for (;;) {
        const bool ok0 = (unsigned)(v0 >> 32) >= (unsigned)s;
        const bool ok1 = (unsigned)(v1 >> 32) >= (unsigned)s;
        if (ok0 && ok1) break;
        if (!ok0) v0 = __hip_atomic_load(rec + pb + tid,       __ATOMIC_RELAXED, __HIP_MEMORY_SCOPE_AGENT);
        if (!ok1) v1 = __hip_atomic_load(rec + pb + tid + 256, __ATOMIC_RELAXED, __HIP_MEMORY_SCOPE_AGENT);
      }
      hs[s & 1][tid]       = __uint_as_float((unsigned)v0);
      hs[s & 1][tid + 256] = __uint_as_float((unsigned)v1);
      __syncthreads();   // the only barrier per step
    }

    // ---- (C) dots: weights are asm-defined; ensure loads retired ----
    asm volatile("s_waitcnt vmcnt(0)" ::: "memory");
    float4 h4[4];
#pragma unroll
    for (int q = 0; q < 4; ++q) h4[q] = *(const float4*)&hs[s & 1][lane * 4 + 128 * q];
    float dsum[6];
#pragma unroll
    for (int rg = 0; rg < 6; ++rg) {
      float a = 0.0f;
#pragma unroll
      for (int q = 0; q < 4; ++q) {
        a += wf[rg][q].x * h4[q].x;
        a += wf[rg][q].y * h4[q].y;
        a += wf[rg][q].z * h4[q].z;
        a += wf[rg][q].w * h4[q].w;
      }
      a += __shfl_xor(a, 1); a += __shfl_xor(a, 2); a += __shfl_xor(a, 4);
      a += __shfl_xor(a, 8); a += __shfl_xor(a, 16);
      dsum[rg] = a;        // full sum in ALL 32 lanes
    }
    const float g = dsum[5];                         // Wlh @ h_prev = G[prevt]

    // ---- (D) gates (all lanes) + relative aggregation (all lanes identical) ----
    const float iv = sigmf(p0 + dsum[0]);
    const float ov = sigmf(p1 + dsum[1]);
    const float sv = sigmf(p2 + dsum[2]);
    const float fv = sigmf(p3 + dsum[3]);
    const float uv = tanhfast(p4 + dsum[4]);
    cstate = fv * cstate + iv * uv;
    const float hb = ov * tanhfast(cstate);

    const float hv_k = (jjU == prevt) ? hprev : Hg;
    const float gv_k = (jjU == prevt) ? g : ((jjU == prevt2) ? gprev : Gg);
    float sm = mkU ? (sigmf(gv_k + p5 + LBg) * hv_k) : 0.0f;
    sm += __shfl_xor(sm, 1); sm += __shfl_xor(sm, 2); sm += __shfl_xor(sm, 4);
    const float hval = hb + sv * tanhfast(sm);       // identical on all 32 lanes

    // ---- (E) publish first (critical path), then plain stores ----
    if (lane == 0) {
      const unsigned long long pk =
          ((unsigned long long)(unsigned)(s + 1) << 32) | (unsigned long long)__float_as_uint(hval);
      __hip_atomic_store(rec + ((s & 1) * 2 + dir) * 512 + m, pk,
                         __ATOMIC_RELAXED, __HIP_MEMORY_SCOPE_AGENT);
      out[(size_t)t * 1024 + dircol + m] = hval;
      if (s > 0) Gbuf[(size_t)prevt * 512 + m] = g;
    }

    // ---- (F) prefetch next step: 1-deep chains (indices already in regs) ----
    if (s < S_LEN - 1) {
      const float HgN  = out[(size_t)jjN * 1024 + dircol + m];
      const float GgN  = Gbuf[(size_t)jjN * 512 + m];
      const float LBgN = lb[(size_t)depN * 512 + m];
      const float* prow = P + (size_t)tn * 3072;
      p0 = prow[m];        p1 = prow[512 + m];  p2 = prow[1024 + m];
      p3 = prow[1536 + m]; p4 = prow[2048 + m]; p5 = prow[2560 + m];
      int jj2 = jjN, mk2 = mkN, dep2 = depN;
      if (s < S_LEN - 2) {
        const int t2 = dir ? (t - 2) : (t + 2);
        jj2 = rel[t2 * KREL + kl]; mk2 = (int)msk[t2 * KREL + kl]; dep2 = dep[t2 * KREL + kl];
      }
      jjU = jjN; mkU = mkN; Hg = HgN; Gg = GgN; LBg = LBgN;
      jjN = jj2; mkN = mk2; depN = dep2;
    }
    hprev = hval; gprev = g;
  }
}

__global__ void k_fill(float* __restrict__ o, int n, float v)
{ const int i = blockIdx.x * 256 + threadIdx.x; if (i < n) o[i] = v; }

extern "C" void kernel_launch(void* const* d_in, const int* in_sizes, int n_in,
                              void* d_out, int out_size, void* d_ws, size_t ws_size,
                              hipStream_t stream)
{
  (void)in_sizes; (void)n_in;
  const float* X     = (const float*)d_in[0];
  const float* Wioux = (const float*)d_in[1];
  const float* bioux = (const float*)d_in[2];
  const float* Wiouh = (const float*)d_in[3];
  const float* biouh = (const float*)d_in[4];
  const float* Wlx   = (const float*)d_in[5];
  const float* blx   = (const float*)d_in[6];
  const float* Wlh   = (const float*)d_in[7];
  const float* blh   = (const float*)d_in[8];
  const float* lb    = (const float*)d_in[9];
  const int* rel_fw  = (const int*)d_in[10];
  const int* dep_fw  = (const int*)d_in[11];
  const unsigned char* mask_fw_raw = (const unsigned char*)d_in[12];
  const int* rel_bw  = (const int*)d_in[13];
  const int* dep_bw  = (const int*)d_in[14];
  const unsigned char* mask_bw_raw = (const unsigned char*)d_in[15];
  float* out = (float*)d_out;

  const int nmask = S_LEN * KREL;                  // 65536
  const size_t needP = (size_t)S_LEN * 3072 * 4;   // 96 MB
  const size_t needG = (size_t)S_LEN * 512 * 4;    // 16 MB each
  const size_t need  = 32768 + needP + 2 * needG + 2 * (size_t)nmask;
  if (ws_size < need) {
    k_fill<<<(out_size + 255) / 256, 256, 0, stream>>>(out, out_size, 12345.0f);
    return;
  }
  char* ws = (char*)d_ws;
  unsigned long long* rec = (unsigned long long*)ws;   // [2 buf][2 dir][512] packets
  float* P   = (float*)(ws + 32768);
  float* Gfw = (float*)(ws + 32768 + needP);
  float* Gbw = Gfw + (size_t)S_LEN * 512;
  unsigned char* Mfw = (unsigned char*)(ws + 32768 + needP + 2 * needG);
  unsigned char* Mbw = Mfw + nmask;

  hipMemsetAsync(rec, 0, 16384, stream);   // tags must start at 0 (ws is poisoned 0xAA)
  k_maskcvt<<<64, 256, 0, stream>>>(mask_fw_raw, Mfw, nmask);
  k_maskcvt<<<64, 256, 0, stream>>>(mask_bw_raw, Mbw, nmask);
  dim3 gg(S_LEN / 64, 3072 / 64);
  k_gemm<<<gg, 256, 0, stream>>>(X, Wioux, Wlx, bioux, biouh, blx, blh, P);
  k_rec<<<2 * WPD, 256, 0, stream>>>(Wiouh, Wlh, P, lb, rel_fw, dep_fw, Mfw,
                                     rel_bw, dep_bw, Mbw, Gfw, Gbw, rec, out);
}

// Round 6
// 19820.308 us; speedup vs baseline: 1.1889x; 1.1889x over previous
//
#include <hip/hip_runtime.h>

#define S_LEN 8192
#define KREL 8
#define WPD 64   // workgroups per direction; each owns 512/WPD = 8 h-columns

typedef float f4 __attribute__((ext_vector_type(4)));

__device__ __forceinline__ float sigmf(float x) { return 1.0f / (1.0f + __expf(-x)); }
__device__ __forceinline__ float tanhfast(float x) { return 1.0f - 2.0f / (__expf(2.0f * x) + 1.0f); }

// ---------------- mask canonicalization (R2-verified) ----------------
__global__ void k_maskcvt(const unsigned char* __restrict__ src,
                          unsigned char* __restrict__ dst, int n)
{
  const unsigned int* w = (const unsigned int*)src;
  __shared__ int s_i32, s_f32;
  if (threadIdx.x == 0) { s_i32 = 1; s_f32 = 1; }
  __syncthreads();
  int i32ok = 1, f32ok = 1;
  for (int i = threadIdx.x; i < 1024; i += blockDim.x) {
    const unsigned int v = w[i];
    if (v != 0u && v != 1u) i32ok = 0;
    if (v != 0u && v != 0x3F800000u) f32ok = 0;
  }
  if (!i32ok) atomicAnd(&s_i32, 0);
  if (!f32ok) atomicAnd(&s_f32, 0);
  __syncthreads();
  const int wide = (s_i32 || s_f32);
  for (int i = blockIdx.x * blockDim.x + threadIdx.x; i < n; i += gridDim.x * blockDim.x)
    dst[i] = wide ? (w[i] ? 1 : 0) : (src[i] ? 1 : 0);
}

// ---------------- parallel precompute (R2-verified) ----------------
__global__ __launch_bounds__(256)
void k_gemm(const float* __restrict__ X, const float* __restrict__ Wioux,
            const float* __restrict__ Wlx, const float* __restrict__ bioux,
            const float* __restrict__ biouh, const float* __restrict__ blx,
            const float* __restrict__ blh, float* __restrict__ P)
{
  __shared__ float As[16][64];
  __shared__ float Bs[16][64];
  const int t0 = blockIdx.x * 64;
  const int r0 = blockIdx.y * 64;
  const int tid = threadIdx.x;
  const int tx = tid & 15, ty = tid >> 4;
  const int si = tid >> 2, sk = (tid & 3) << 2;
  const int rB = r0 + si;
  const float* brow = (rB < 2560) ? (Wioux + (size_t)rB * 512)
                                  : (Wlx + (size_t)(rB - 2560) * 512);
  const float* arow = X + (size_t)(t0 + si) * 512;
  float acc[4][4] = {};
  for (int k0 = 0; k0 < 512; k0 += 16) {
    const float4 av = *(const float4*)(arow + k0 + sk);
    const float4 bv = *(const float4*)(brow + k0 + sk);
    __syncthreads();
    As[sk + 0][si] = av.x; As[sk + 1][si] = av.y; As[sk + 2][si] = av.z; As[sk + 3][si] = av.w;
    Bs[sk + 0][si] = bv.x; Bs[sk + 1][si] = bv.y; Bs[sk + 2][si] = bv.z; Bs[sk + 3][si] = bv.w;
    __syncthreads();
#pragma unroll
    for (int kk = 0; kk < 16; ++kk) {
      const float4 a = *(const float4*)&As[kk][ty * 4];
      const float4 b = *(const float4*)&Bs[kk][tx * 4];
      acc[0][0] += a.x * b.x; acc[0][1] += a.x * b.y; acc[0][2] += a.x * b.z; acc[0][3] += a.x * b.w;
      acc[1][0] += a.y * b.x; acc[1][1] += a.y * b.y; acc[1][2] += a.y * b.z; acc[1][3] += a.y * b.w;
      acc[2][0] += a.z * b.x; acc[2][1] += a.z * b.y; acc[2][2] += a.z * b.z; acc[2][3] += a.z * b.w;
      acc[3][0] += a.w * b.x; acc[3][1] += a.w * b.y; acc[3][2] += a.w * b.z; acc[3][3] += a.w * b.w;
    }
  }
#pragma unroll
  for (int i = 0; i < 4; ++i) {
    const int t = t0 + ty * 4 + i;
#pragma unroll
    for (int j = 0; j < 4; ++j) {
      const int r = r0 + tx * 4 + j;
      const float bias = (r < 2560) ? (bioux[r] + biouh[r]) : (blx[r - 2560] + blh[r - 2560]);
      P[(size_t)t * 3072 + r] = acc[i][j] + bias;
    }
  }
}

// ---------------- persistent recurrent kernel, v4: LDS-resident weights ----------------
// Weights (96 KB/WG) staged into dynamic LDS once. Per step, 24 ds_read_b128 are
// issued via asm BEFORE the packet poll: ds_read counts on lgkmcnt, the poll's
// vmcnt waits don't serialize behind it (the R5 failure mode). LDS reads land
// inside the poll-spin shadow; one s_waitcnt lgkmcnt(0) before the dots.
__global__ __launch_bounds__(256, 1)
void k_rec(const float* __restrict__ Wiouh, const float* __restrict__ Wlh,
           const float* __restrict__ P, const float* __restrict__ lb,
           const int* __restrict__ rel_fw, const int* __restrict__ dep_fw,
           const unsigned char* __restrict__ mask_fw,
           const int* __restrict__ rel_bw, const int* __restrict__ dep_bw,
           const unsigned char* __restrict__ mask_bw,
           float* __restrict__ Gfw, float* __restrict__ Gbw,
           unsigned long long* rec, float* __restrict__ out)
{
  extern __shared__ float wlds[];      // [8 grp][6 rg][512] = 96 KB dynamic
  const int wg  = blockIdx.x;
  const int dir = wg / WPD;
  const int w   = wg % WPD;
  const int tid = threadIdx.x;
  const int grp = tid >> 5;            // 8 column-groups per WG
  const int lane = tid & 31;           // 32 lanes per column
  const int kl = lane & 7;             // owned relative slot (octets duplicate)
  const int m = w * 8 + grp;           // owned h-column
  const int dircol = dir * 512;
  const int* rel = dir ? rel_bw : rel_fw;
  const int* dep = dir ? dep_bw : dep_fw;
  const unsigned char* msk = dir ? mask_bw : mask_fw;
  float* Gbuf = dir ? Gbw : Gfw;

  // ---- one-time weight staging into LDS (each thread fills what it will read) ----
  {
    const float* rows[6];
#pragma unroll
    for (int rg = 0; rg < 5; ++rg) rows[rg] = Wiouh + (size_t)(rg * 512 + m) * 512 + lane * 4;
    rows[5] = Wlh + (size_t)m * 512 + lane * 4;
#pragma unroll
    for (int rg = 0; rg < 6; ++rg)
#pragma unroll
      for (int q = 0; q < 4; ++q)
        *(f4*)&wlds[(size_t)grp * 3072 + rg * 512 + q * 128 + lane * 4] =
            *(const f4*)(rows[rg] + q * 128);
  }
  const unsigned wbase = (unsigned)(uintptr_t)&wlds[(size_t)grp * 3072 + lane * 4];

  __shared__ float hs[2][512];
  hs[0][tid] = 0.0f; hs[0][tid + 256] = 0.0f;

  float cstate = 0.0f, hprev = 0.0f, gprev = 0.0f;

  // ---- prologue: step-0 gathers (dead: first step fully masked) + step-1 indices ----
  int jjU, mkU, jjN, mkN, depN;
  float Hg, Gg, LBg;
  float p0, p1, p2, p3, p4, p5;
  {
    const int t0 = dir ? (S_LEN - 1) : 0;
    const int t1 = dir ? (S_LEN - 2) : 1;
    jjU = rel[t0 * KREL + kl]; mkU = (int)msk[t0 * KREL + kl];
    Hg  = out[(size_t)jjU * 1024 + dircol + m];
    Gg  = Gbuf[(size_t)jjU * 512 + m];
    LBg = lb[(size_t)dep[t0 * KREL + kl] * 512 + m];
    const float* prow = P + (size_t)t0 * 3072;
    p0 = prow[m];        p1 = prow[512 + m];  p2 = prow[1024 + m];
    p3 = prow[1536 + m]; p4 = prow[2048 + m]; p5 = prow[2560 + m];
    jjN = rel[t1 * KREL + kl]; mkN = (int)msk[t1 * KREL + kl]; depN = dep[t1 * KREL + kl];
  }
  __syncthreads();   // weights staged + hs zeroed

#pragma unroll 1
  for (int s = 0; s < S_LEN; ++s) {
    const int t = dir ? (S_LEN - 1 - s) : s;
    const int tn = dir ? (t - 1) : (t + 1);
    const int prevt  = dir ? (t + 1) : (t - 1);   // matches jj only when s>0
    const int prevt2 = dir ? (t + 2) : (t - 2);

    // ---- (A) issue weight ds_reads NOW; they ride lgkmcnt, landing under the poll ----
    f4 wf[6][4];
#pragma unroll
    for (int rg = 0; rg < 6; ++rg)
#pragma unroll
      for (int q = 0; q < 4; ++q)
        asm volatile("ds_read_b128 %0, %1 offset:%2"
                     : "=v"(wf[rg][q])
                     : "v"(wbase), "i"((rg * 512 + q * 128) * 4)
                     : "memory");

    // ---- (B) poll packets (vmcnt only), broadcast h through LDS ----
    if (s > 0) {
      const int pb = (((s - 1) & 1) * 2 + dir) * 512;
      unsigned long long v0 = __hip_atomic_load(rec + pb + tid,       __ATOMIC_RELAXED, __HIP_MEMORY_SCOPE_AGENT);
      unsigned long long v1 = __hip_atomic_load(rec + pb + tid + 256, __ATOMIC_RELAXED, __HIP_MEMORY_SCOPE_AGENT);
      for (;;) {
        const bool ok0 = (unsigned)(v0 >> 32) >= (unsigned)s;
        const bool ok1 = (unsigned)(v1 >> 32) >= (unsigned)s;
        if (ok0 && ok1) break;
        if (!ok0) v0 = __hip_atomic_load(rec + pb + tid,       __ATOMIC_RELAXED, __HIP_MEMORY_SCOPE_AGENT);
        if (!ok1) v1 = __hip_atomic_load(rec + pb + tid + 256, __ATOMIC_RELAXED, __HIP_MEMORY_SCOPE_AGENT);
      }
      hs[s & 1][tid]       = __uint_as_float((unsigned)v0);
      hs[s & 1][tid + 256] = __uint_as_float((unsigned)v1);
      __syncthreads();   // the only barrier per step
    }

    // ---- (C) dots ----
    asm volatile("s_waitcnt lgkmcnt(0)" ::: "memory");
    float4 h4[4];
#pragma unroll
    for (int q = 0; q < 4; ++q) h4[q] = *(const float4*)&hs[s & 1][lane * 4 + 128 * q];
    float dsum[6];
#pragma unroll
    for (int rg = 0; rg < 6; ++rg) {
      float a = 0.0f;
#pragma unroll
      for (int q = 0; q < 4; ++q) {
        a += wf[rg][q].x * h4[q].x;
        a += wf[rg][q].y * h4[q].y;
        a += wf[rg][q].z * h4[q].z;
        a += wf[rg][q].w * h4[q].w;
      }
      a += __shfl_xor(a, 1); a += __shfl_xor(a, 2); a += __shfl_xor(a, 4);
      a += __shfl_xor(a, 8); a += __shfl_xor(a, 16);
      dsum[rg] = a;        // full sum in ALL 32 lanes
    }
    const float g = dsum[5];                         // Wlh @ h_prev = G[prevt]

    // ---- (D) gates + relative aggregation (identical on all lanes) ----
    const float iv = sigmf(p0 + dsum[0]);
    const float ov = sigmf(p1 + dsum[1]);
    const float sv = sigmf(p2 + dsum[2]);
    const float fv = sigmf(p3 + dsum[3]);
    const float uv = tanhfast(p4 + dsum[4]);
    cstate = fv * cstate + iv * uv;
    const float hb = ov * tanhfast(cstate);

    const float hv_k = (jjU == prevt) ? hprev : Hg;
    const float gv_k = (jjU == prevt) ? g : ((jjU == prevt2) ? gprev : Gg);
    float sm = mkU ? (sigmf(gv_k + p5 + LBg) * hv_k) : 0.0f;
    sm += __shfl_xor(sm, 1); sm += __shfl_xor(sm, 2); sm += __shfl_xor(sm, 4);
    const float hval = hb + sv * tanhfast(sm);

    // ---- (E) publish first (critical path), then plain stores ----
    if (lane == 0) {
      const unsigned long long pk =
          ((unsigned long long)(unsigned)(s + 1) << 32) | (unsigned long long)__float_as_uint(hval);
      __hip_atomic_store(rec + ((s & 1) * 2 + dir) * 512 + m, pk,
                         __ATOMIC_RELAXED, __HIP_MEMORY_SCOPE_AGENT);
      out[(size_t)t * 1024 + dircol + m] = hval;
      if (s > 0) Gbuf[(size_t)prevt * 512 + m] = g;
    }

    // ---- (F) prefetch next step: 1-deep chains (indices already in regs) ----
    if (s < S_LEN - 1) {
      const float HgN  = out[(size_t)jjN * 1024 + dircol + m];
      const float GgN  = Gbuf[(size_t)jjN * 512 + m];
      const float LBgN = lb[(size_t)depN * 512 + m];
      const float* prow = P + (size_t)tn * 3072;
      p0 = prow[m];        p1 = prow[512 + m];  p2 = prow[1024 + m];
      p3 = prow[1536 + m]; p4 = prow[2048 + m]; p5 = prow[2560 + m];
      int jj2 = jjN, mk2 = mkN, dep2 = depN;
      if (s < S_LEN - 2) {
        const int t2 = dir ? (t - 2) : (t + 2);
        jj2 = rel[t2 * KREL + kl]; mk2 = (int)msk[t2 * KREL + kl]; dep2 = dep[t2 * KREL + kl];
      }
      jjU = jjN; mkU = mkN; Hg = HgN; Gg = GgN; LBg = LBgN;
      jjN = jj2; mkN = mk2; depN = dep2;
    }
    hprev = hval; gprev = g;
  }
}

// ---------------- fallback (R5 structure, global-load weights) ----------------
// Launched only if >64KB dynamic-LDS opt-in fails; guarantees a passing round.
__global__ __launch_bounds__(256, 1)
void k_rec_glb(const float* __restrict__ Wiouh, const float* __restrict__ Wlh,
               const float* __restrict__ P, const float* __restrict__ lb,
               const int* __restrict__ rel_fw, const int* __restrict__ dep_fw,
               const unsigned char* __restrict__ mask_fw,
               const int* __restrict__ rel_bw, const int* __restrict__ dep_bw,
               const unsigned char* __restrict__ mask_bw,
               float* __restrict__ Gfw, float* __restrict__ Gbw,
               unsigned long long* rec, float* __restrict__ out)
{
  const int wg  = blockIdx.x;
  const int dir = wg / WPD;
  const int w   = wg % WPD;
  const int tid = threadIdx.x;
  const int grp = tid >> 5;
  const int lane = tid & 31;
  const int kl = lane & 7;
  const int m = w * 8 + grp;
  const int dircol = dir * 512;
  const int* rel = dir ? rel_bw : rel_fw;
  const int* dep = dir ? dep_bw : dep_fw;
  const unsigned char* msk = dir ? mask_bw : mask_fw;
  float* Gbuf = dir ? Gbw : Gfw;

  const float* wrow[6];
#pragma unroll
  for (int rg = 0; rg < 5; ++rg) wrow[rg] = Wiouh + (size_t)(rg * 512 + m) * 512 + lane * 4;
  wrow[5] = Wlh + (size_t)m * 512 + lane * 4;

  __shared__ float hs[2][512];
  hs[0][tid] = 0.0f; hs[0][tid + 256] = 0.0f;
  float cstate = 0.0f, hprev = 0.0f, gprev = 0.0f;

  int jjU, mkU, jjN, mkN, depN;
  float Hg, Gg, LBg, p0, p1, p2, p3, p4, p5;
  {
    const int t0 = dir ? (S_LEN - 1) : 0;
    const int t1 = dir ? (S_LEN - 2) : 1;
    jjU = rel[t0 * KREL + kl]; mkU = (int)msk[t0 * KREL + kl];
    Hg  = out[(size_t)jjU * 1024 + dircol + m];
    Gg  = Gbuf[(size_t)jjU * 512 + m];
    LBg = lb[(size_t)dep[t0 * KREL + kl] * 512 + m];
    const float* prow = P + (size_t)t0 * 3072;
    p0 = prow[m]; p1 = prow[512 + m]; p2 = prow[1024 + m];
    p3 = prow[1536 + m]; p4 = prow[2048 + m]; p5 = prow[2560 + m];
    jjN = rel[t1 * KREL + kl]; mkN = (int)msk[t1 * KREL + kl]; depN = dep[t1 * KREL + kl];
  }
  __syncthreads();

#pragma unroll 1
  for (int s = 0; s < S_LEN; ++s) {
    const int t = dir ? (S_LEN - 1 - s) : s;
    const int tn = dir ? (t - 1) : (t + 1);
    const int prevt  = dir ? (t + 1) : (t - 1);
    const int prevt2 = dir ? (t + 2) : (t - 2);

    f4 wf[6][4];
#pragma unroll
    for (int rg = 0; rg < 6; ++rg)
      asm volatile("global_load_dwordx4 %0, %4, off\n\t"
                   "global_load_dwordx4 %1, %4, off offset:512\n\t"
                   "global_load_dwordx4 %2, %4, off offset:1024\n\t"
                   "global_load_dwordx4 %3, %4, off offset:1536"
                   : "=v"(wf[rg][0]), "=v"(wf[rg][1]), "=v"(wf[rg][2]), "=v"(wf[rg][3])
                   : "v"(wrow[rg]) : "memory");

    if (s > 0) {
      const int pb = (((s - 1) & 1) * 2 + dir) * 512;
      unsigned long long v0 = __hip_atomic_load(rec + pb + tid,       __ATOMIC_RELAXED, __HIP_MEMORY_SCOPE_AGENT);
      unsigned long long v1 = __hip_atomic_load(rec + pb + tid + 256, __ATOMIC_RELAXED, __HIP_MEMORY_SCOPE_AGENT);
      for (;;) {
        const bool ok0 = (unsigned)(v0 >> 32) >= (unsigned)s;
        const bool ok1 = (unsigned)(v1 >> 32) >= (unsigned)s;
        if (ok0 && ok1) break;
        if (!ok0) v0 = __hip_atomic_load(rec + pb + tid,       __ATOMIC_RELAXED, __HIP_MEMORY_SCOPE_AGENT);
        if (!ok1) v1 = __hip_atomic_load(rec + pb + tid + 256, __ATOMIC_RELAXED, __HIP_MEMORY_SCOPE_AGENT);
      }
      hs[s & 1][tid]       = __uint_as_float((unsigned)v0);
      hs[s & 1][tid + 256] = __uint_as_float((unsigned)v1);
      __syncthreads();
    }

    asm volatile("s_waitcnt vmcnt(0)" ::: "memory");
    float4 h4[4];
#pragma unroll
    for (int q = 0; q < 4; ++q) h4[q] = *(const float4*)&hs[s & 1][lane * 4 + 128 * q];
    float dsum[6];
#pragma unroll
    for (int rg = 0; rg < 6; ++rg) {
      float a = 0.0f;
#pragma unroll
      for (int q = 0; q < 4; ++q) {
        a += wf[rg][q].x * h4[q].x; a += wf[rg][q].y * h4[q].y;
        a += wf[rg][q].z * h4[q].z; a += wf[rg][q].w * h4[q].w;
      }
      a += __shfl_xor(a, 1); a += __shfl_xor(a, 2); a += __shfl_xor(a, 4);
      a += __shfl_xor(a, 8); a += __shfl_xor(a, 16);
      dsum[rg] = a;
    }
    const float g = dsum[5];
    const float iv = sigmf(p0 + dsum[0]);
    const float ov = sigmf(p1 + dsum[1]);
    const float sv = sigmf(p2 + dsum[2]);
    const float fv = sigmf(p3 + dsum[3]);
    const float uv = tanhfast(p4 + dsum[4]);
    cstate = fv * cstate + iv * uv;
    const float hb = ov * tanhfast(cstate);
    const float hv_k = (jjU == prevt) ? hprev : Hg;
    const float gv_k = (jjU == prevt) ? g : ((jjU == prevt2) ? gprev : Gg);
    float sm = mkU ? (sigmf(gv_k + p5 + LBg) * hv_k) : 0.0f;
    sm += __shfl_xor(sm, 1); sm += __shfl_xor(sm, 2); sm += __shfl_xor(sm, 4);
    const float hval = hb + sv * tanhfast(sm);

    if (lane == 0) {
      const unsigned long long pk =
          ((unsigned long long)(unsigned)(s + 1) << 32) | (unsigned long long)__float_as_uint(hval);
      __hip_atomic_store(rec + ((s & 1) * 2 + dir) * 512 + m, pk,
                         __ATOMIC_RELAXED, __HIP_MEMORY_SCOPE_AGENT);
      out[(size_t)t * 1024 + dircol + m] = hval;
      if (s > 0) Gbuf[(size_t)prevt * 512 + m] = g;
    }
    if (s < S_LEN - 1) {
      const float HgN  = out[(size_t)jjN * 1024 + dircol + m];
      const float GgN  = Gbuf[(size_t)jjN * 512 + m];
      const float LBgN = lb[(size_t)depN * 512 + m];
      const float* prow = P + (size_t)tn * 3072;
      p0 = prow[m]; p1 = prow[512 + m]; p2 = prow[1024 + m];
      p3 = prow[1536 + m]; p4 = prow[2048 + m]; p5 = prow[2560 + m];
      int jj2 = jjN, mk2 = mkN, dep2 = depN;
      if (s < S_LEN - 2) {
        const int t2 = dir ? (t - 2) : (t + 2);
        jj2 = rel[t2 * KREL + kl]; mk2 = (int)msk[t2 * KREL + kl]; dep2 = dep[t2 * KREL + kl];
      }
      jjU = jjN; mkU = mkN; Hg = HgN; Gg = GgN; LBg = LBgN;
      jjN = jj2; mkN = mk2; depN = dep2;
    }
    hprev = hval; gprev = g;
  }
}

__global__ void k_fill(float* __restrict__ o, int n, float v)
{ const int i = blockIdx.x * 256 + threadIdx.x; if (i < n) o[i] = v; }

extern "C" void kernel_launch(void* const* d_in, const int* in_sizes, int n_in,
                              void* d_out, int out_size, void* d_ws, size_t ws_size,
                              hipStream_t stream)
{
  (void)in_sizes; (void)n_in;
  const float* X     = (const float*)d_in[0];
  const float* Wioux = (const float*)d_in[1];
  const float* bioux = (const float*)d_in[2];
  const float* Wiouh = (const float*)d_in[3];
  const float* biouh = (const float*)d_in[4];
  const float* Wlx   = (const float*)d_in[5];
  const float* blx   = (const float*)d_in[6];
  const float* Wlh   = (const float*)d_in[7];
  const float* blh   = (const float*)d_in[8];
  const float* lb    = (const float*)d_in[9];
  const int* rel_fw  = (const int*)d_in[10];
  const int* dep_fw  = (const int*)d_in[11];
  const unsigned char* mask_fw_raw = (const unsigned char*)d_in[12];
  const int* rel_bw  = (const int*)d_in[13];
  const int* dep_bw  = (const int*)d_in[14];
  const unsigned char* mask_bw_raw = (const unsigned char*)d_in[15];
  float* out = (float*)d_out;

  const int nmask = S_LEN * KREL;                  // 65536
  const size_t needP = (size_t)S_LEN * 3072 * 4;   // 96 MB
  const size_t needG = (size_t)S_LEN * 512 * 4;    // 16 MB each
  const size_t need  = 32768 + needP + 2 * needG + 2 * (size_t)nmask;
  if (ws_size < need) {
    k_fill<<<(out_size + 255) / 256, 256, 0, stream>>>(out, out_size, 12345.0f);
    return;
  }
  char* ws = (char*)d_ws;
  unsigned long long* rec = (unsigned long long*)ws;   // [2 buf][2 dir][512] packets
  float* P   = (float*)(ws + 32768);
  float* Gfw = (float*)(ws + 32768 + needP);
  float* Gbw = Gfw + (size_t)S_LEN * 512;
  unsigned char* Mfw = (unsigned char*)(ws + 32768 + needP + 2 * needG);
  unsigned char* Mbw = Mfw + nmask;

  hipMemsetAsync(rec, 0, 16384, stream);   // tags must start at 0 (ws is poisoned 0xAA)
  k_maskcvt<<<64, 256, 0, stream>>>(mask_fw_raw, Mfw, nmask);
  k_maskcvt<<<64, 256, 0, stream>>>(mask_bw_raw, Mbw, nmask);
  dim3 gg(S_LEN / 64, 3072 / 64);
  k_gemm<<<gg, 256, 0, stream>>>(X, Wioux, Wlx, bioux, biouh, blx, blh, P);

  const int dyn_lds = 8 * 6 * 512 * 4;     // 96 KB weight tile per WG
  static hipError_t attr_err = hipFuncSetAttribute(
      (const void*)k_rec, hipFuncAttributeMaxDynamicSharedMemorySize, dyn_lds);
  if (attr_err == hipSuccess) {
    k_rec<<<2 * WPD, 256, dyn_lds, stream>>>(Wiouh, Wlh, P, lb, rel_fw, dep_fw, Mfw,
                                             rel_bw, dep_bw, Mbw, Gfw, Gbw, rec, out);
  } else {
    k_rec_glb<<<2 * WPD, 256, 0, stream>>>(Wiouh, Wlh, P, lb, rel_fw, dep_fw, Mfw,
                                           rel_bw, dep_bw, Mbw, Gfw, Gbw, rec, out);
  }
}

// Round 8
// 18653.322 us; speedup vs baseline: 1.2633x; 1.0626x over previous
//
#include <hip/hip_runtime.h>

#define S_LEN 8192
#define KREL 8
#define WPD 128  // workgroups per direction; each owns 512/WPD = 4 h-columns

typedef float f4 __attribute__((ext_vector_type(4)));
typedef unsigned long long u64;

__device__ __forceinline__ float sigmf(float x) { return 1.0f / (1.0f + __expf(-x)); }
__device__ __forceinline__ float tanhfast(float x) { return 1.0f - 2.0f / (__expf(2.0f * x) + 1.0f); }

// ---------------- mask canonicalization (R2-verified) ----------------
__global__ void k_maskcvt(const unsigned char* __restrict__ src,
                          unsigned char* __restrict__ dst, int n)
{
  const unsigned int* w = (const unsigned int*)src;
  __shared__ int s_i32, s_f32;
  if (threadIdx.x == 0) { s_i32 = 1; s_f32 = 1; }
  __syncthreads();
  int i32ok = 1, f32ok = 1;
  for (int i = threadIdx.x; i < 1024; i += blockDim.x) {
    const unsigned int v = w[i];
    if (v != 0u && v != 1u) i32ok = 0;
    if (v != 0u && v != 0x3F800000u) f32ok = 0;
  }
  if (!i32ok) atomicAnd(&s_i32, 0);
  if (!f32ok) atomicAnd(&s_f32, 0);
  __syncthreads();
  const int wide = (s_i32 || s_f32);
  for (int i = blockIdx.x * blockDim.x + threadIdx.x; i < n; i += gridDim.x * blockDim.x)
    dst[i] = wide ? (w[i] ? 1 : 0) : (src[i] ? 1 : 0);
}

// ---------------- parallel precompute (R2-verified) ----------------
__global__ __launch_bounds__(256)
void k_gemm(const float* __restrict__ X, const float* __restrict__ Wioux,
            const float* __restrict__ Wlx, const float* __restrict__ bioux,
            const float* __restrict__ biouh, const float* __restrict__ blx,
            const float* __restrict__ blh, float* __restrict__ P)
{
  __shared__ float As[16][64];
  __shared__ float Bs[16][64];
  const int t0 = blockIdx.x * 64;
  const int r0 = blockIdx.y * 64;
  const int tid = threadIdx.x;
  const int tx = tid & 15, ty = tid >> 4;
  const int si = tid >> 2, sk = (tid & 3) << 2;
  const int rB = r0 + si;
  const float* brow = (rB < 2560) ? (Wioux + (size_t)rB * 512)
                                  : (Wlx + (size_t)(rB - 2560) * 512);
  const float* arow = X + (size_t)(t0 + si) * 512;
  float acc[4][4] = {};
  for (int k0 = 0; k0 < 512; k0 += 16) {
    const float4 av = *(const float4*)(arow + k0 + sk);
    const float4 bv = *(const float4*)(brow + k0 + sk);
    __syncthreads();
    As[sk + 0][si] = av.x; As[sk + 1][si] = av.y; As[sk + 2][si] = av.z; As[sk + 3][si] = av.w;
    Bs[sk + 0][si] = bv.x; Bs[sk + 1][si] = bv.y; Bs[sk + 2][si] = bv.z; Bs[sk + 3][si] = bv.w;
    __syncthreads();
#pragma unroll
    for (int kk = 0; kk < 16; ++kk) {
      const float4 a = *(const float4*)&As[kk][ty * 4];
      const float4 b = *(const float4*)&Bs[kk][tx * 4];
      acc[0][0] += a.x * b.x; acc[0][1] += a.x * b.y; acc[0][2] += a.x * b.z; acc[0][3] += a.x * b.w;
      acc[1][0] += a.y * b.x; acc[1][1] += a.y * b.y; acc[1][2] += a.y * b.z; acc[1][3] += a.y * b.w;
      acc[2][0] += a.z * b.x; acc[2][1] += a.z * b.y; acc[2][2] += a.z * b.z; acc[2][3] += a.z * b.w;
      acc[3][0] += a.w * b.x; acc[3][1] += a.w * b.y; acc[3][2] += a.w * b.z; acc[3][3] += a.w * b.w;
    }
  }
#pragma unroll
  for (int i = 0; i < 4; ++i) {
    const int t = t0 + ty * 4 + i;
#pragma unroll
    for (int j = 0; j < 4; ++j) {
      const int r = r0 + tx * 4 + j;
      const float bias = (r < 2560) ? (bioux[r] + biouh[r]) : (blx[r - 2560] + blh[r - 2560]);
      P[(size_t)t * 3072 + r] = acc[i][j] + bias;
    }
  }
}

// ---------------- persistent recurrent kernel v6 ----------------
// R6 structure verbatim (verified correct), re-partitioned: WPD=128 -> 256 WGs,
// 4 columns/WG, 64 lanes/column. Per-CU per-step work halves (12 ds_read_b128
// + 48 FMA per thread vs 24 + 96). Weights now fit STATIC LDS (48 KB) -- no
// dynamic-LDS attribute (R7's launch-failure suspect is deleted).
// Sync: 64-bit {h,tag} packets, parity double-buffered, relaxed agent atomics.
// Gather patches at use time: Hg jj==prevt->hprev; Gg jj==prevt->g, prevt2->gprev.
__global__ __launch_bounds__(256, 1)
void k_rec(const float* __restrict__ Wiouh, const float* __restrict__ Wlh,
           const float* __restrict__ P, const float* __restrict__ lb,
           const int* __restrict__ rel_fw, const int* __restrict__ dep_fw,
           const unsigned char* __restrict__ mask_fw,
           const int* __restrict__ rel_bw, const int* __restrict__ dep_bw,
           const unsigned char* __restrict__ mask_bw,
           float* __restrict__ Gfw, float* __restrict__ Gbw,
           u64* rec, float* __restrict__ out)
{
  __shared__ float wlds[4 * 6 * 512];   // 48 KB static weight tile
  __shared__ float hs[2][512];
  const int wg  = blockIdx.x;
  const int dir = wg / WPD;
  const int w   = wg % WPD;
  const int tid = threadIdx.x;
  const int grp = tid >> 6;            // 4 column-groups per WG (one wave each)
  const int lane = tid & 63;           // 64 lanes per column
  const int kl = lane & 7;             // owned relative slot (8 octets duplicate)
  const int m = w * 4 + grp;           // owned h-column
  const int dircol = dir * 512;
  const int* rel = dir ? rel_bw : rel_fw;
  const int* dep = dir ? dep_bw : dep_fw;
  const unsigned char* msk = dir ? mask_bw : mask_fw;
  float* Gbuf = dir ? Gbw : Gfw;

  // ---- one-time weight staging into LDS (each thread fills what it will read) ----
  {
    const float* rows[6];
#pragma unroll
    for (int rg = 0; rg < 5; ++rg) rows[rg] = Wiouh + (size_t)(rg * 512 + m) * 512;
    rows[5] = Wlh + (size_t)m * 512;
#pragma unroll
    for (int rg = 0; rg < 6; ++rg)
#pragma unroll
      for (int q = 0; q < 2; ++q)
        *(f4*)&wlds[(size_t)grp * 3072 + rg * 512 + q * 256 + lane * 4] =
            *(const f4*)(rows[rg] + q * 256 + lane * 4);
  }
  const unsigned wbase = (unsigned)(uintptr_t)&wlds[(size_t)grp * 3072 + lane * 4];

  hs[0][tid] = 0.0f; hs[0][tid + 256] = 0.0f;

  float cstate = 0.0f, hprev = 0.0f, gprev = 0.0f;

  // ---- prologue: step-0 gathers (dead: first step fully masked) + step-1 indices ----
  int jjU, mkU, jjN, mkN, depN;
  float Hg, Gg, LBg;
  float p0, p1, p2, p3, p4, p5;
  {
    const int t0 = dir ? (S_LEN - 1) : 0;
    const int t1 = dir ? (S_LEN - 2) : 1;
    jjU = rel[t0 * KREL + kl]; mkU = (int)msk[t0 * KREL + kl];
    Hg  = out[(size_t)jjU * 1024 + dircol + m];
    Gg  = Gbuf[(size_t)jjU * 512 + m];
    LBg = lb[(size_t)dep[t0 * KREL + kl] * 512 + m];
    const float* prow = P + (size_t)t0 * 3072;
    p0 = prow[m];        p1 = prow[512 + m];  p2 = prow[1024 + m];
    p3 = prow[1536 + m]; p4 = prow[2048 + m]; p5 = prow[2560 + m];
    jjN = rel[t1 * KREL + kl]; mkN = (int)msk[t1 * KREL + kl]; depN = dep[t1 * KREL + kl];
  }
  __syncthreads();   // weights staged + hs zeroed

#pragma unroll 1
  for (int s = 0; s < S_LEN; ++s) {
    const int t = dir ? (S_LEN - 1 - s) : s;
    const int tn = dir ? (t - 1) : (t + 1);
    const int prevt  = dir ? (t + 1) : (t - 1);   // matches jj only when s>0
    const int prevt2 = dir ? (t + 2) : (t - 2);

    // ---- (A) issue weight ds_reads NOW (lgkmcnt; land under the poll) ----
    f4 wf[6][2];
#pragma unroll
    for (int rg = 0; rg < 6; ++rg)
#pragma unroll
      for (int q = 0; q < 2; ++q)
        asm volatile("ds_read_b128 %0, %1 offset:%2"
                     : "=v"(wf[rg][q])
                     : "v"(wbase), "i"((rg * 512 + q * 256) * 4)
                     : "memory");

    // ---- (B) poll packets (vmcnt only), broadcast h through LDS ----
    if (s > 0) {
      const int pb = (((s - 1) & 1) * 2 + dir) * 512;
      u64 v0 = __hip_atomic_load(rec + pb + tid,       __ATOMIC_RELAXED, __HIP_MEMORY_SCOPE_AGENT);
      u64 v1 = __hip_atomic_load(rec + pb + tid + 256, __ATOMIC_RELAXED, __HIP_MEMORY_SCOPE_AGENT);
      for (;;) {
        const bool ok0 = (unsigned)(v0 >> 32) >= (unsigned)s;
        const bool ok1 = (unsigned)(v1 >> 32) >= (unsigned)s;
        if (ok0 && ok1) break;
        if (!ok0) v0 = __hip_atomic_load(rec + pb + tid,       __ATOMIC_RELAXED, __HIP_MEMORY_SCOPE_AGENT);
        if (!ok1) v1 = __hip_atomic_load(rec + pb + tid + 256, __ATOMIC_RELAXED, __HIP_MEMORY_SCOPE_AGENT);
      }
      hs[s & 1][tid]       = __uint_as_float((unsigned)v0);
      hs[s & 1][tid + 256] = __uint_as_float((unsigned)v1);
      __syncthreads();   // the only barrier per step
    }

    // ---- (C) dots: 6 owned rows x 8 elems/lane, butterfly over 64 lanes ----
    asm volatile("s_waitcnt lgkmcnt(0)" ::: "memory");
    float4 h4[2];
#pragma unroll
    for (int q = 0; q < 2; ++q) h4[q] = *(const float4*)&hs[s & 1][lane * 4 + 256 * q];
    float dsum[6];
#pragma unroll
    for (int rg = 0; rg < 6; ++rg) {
      float a = 0.0f;
#pragma unroll
      for (int q = 0; q < 2; ++q) {
        a += wf[rg][q].x * h4[q].x;
        a += wf[rg][q].y * h4[q].y;
        a += wf[rg][q].z * h4[q].z;
        a += wf[rg][q].w * h4[q].w;
      }
      a += __shfl_xor(a, 1);  a += __shfl_xor(a, 2);  a += __shfl_xor(a, 4);
      a += __shfl_xor(a, 8);  a += __shfl_xor(a, 16); a += __shfl_xor(a, 32);
      dsum[rg] = a;            // full sum in ALL 64 lanes
    }
    const float g = dsum[5];   // Wlh @ h_prev = G[prevt]

    // ---- (D) gates + relative aggregation (identical on all lanes) ----
    const float iv = sigmf(p0 + dsum[0]);
    const float ov = sigmf(p1 + dsum[1]);
    const float sv = sigmf(p2 + dsum[2]);
    const float fv = sigmf(p3 + dsum[3]);
    const float uv = tanhfast(p4 + dsum[4]);
    cstate = fv * cstate + iv * uv;
    const float hb = ov * tanhfast(cstate);

    const float hv_k = (jjU == prevt) ? hprev : Hg;
    const float gv_k = (jjU == prevt) ? g : ((jjU == prevt2) ? gprev : Gg);
    float sm = mkU ? (sigmf(gv_k + p5 + LBg) * hv_k) : 0.0f;
    sm += __shfl_xor(sm, 1); sm += __shfl_xor(sm, 2); sm += __shfl_xor(sm, 4);
    const float hval = hb + sv * tanhfast(sm);

    // ---- (E) publish first (critical path), then plain stores ----
    if (lane == 0) {
      const u64 pk =
          ((u64)(unsigned)(s + 1) << 32) | (u64)__float_as_uint(hval);
      __hip_atomic_store(rec + ((s & 1) * 2 + dir) * 512 + m, pk,
                         __ATOMIC_RELAXED, __HIP_MEMORY_SCOPE_AGENT);
      out[(size_t)t * 1024 + dircol + m] = hval;
      if (s > 0) Gbuf[(size_t)prevt * 512 + m] = g;
    }

    // ---- (F) prefetch next step: 1-deep chains (indices already in regs) ----
    if (s < S_LEN - 1) {
      const float HgN  = out[(size_t)jjN * 1024 + dircol + m];
      const float GgN  = Gbuf[(size_t)jjN * 512 + m];
      const float LBgN = lb[(size_t)depN * 512 + m];
      const float* prow = P + (size_t)tn * 3072;
      p0 = prow[m];        p1 = prow[512 + m];  p2 = prow[1024 + m];
      p3 = prow[1536 + m]; p4 = prow[2048 + m]; p5 = prow[2560 + m];
      int jj2 = jjN, mk2 = mkN, dep2 = depN;
      if (s < S_LEN - 2) {
        const int t2 = dir ? (t - 2) : (t + 2);
        jj2 = rel[t2 * KREL + kl]; mk2 = (int)msk[t2 * KREL + kl]; dep2 = dep[t2 * KREL + kl];
      }
      jjU = jjN; mkU = mkN; Hg = HgN; Gg = GgN; LBg = LBgN;
      jjN = jj2; mkN = mk2; depN = dep2;
    }
    hprev = hval; gprev = g;
  }
}

__global__ void k_fill(float* __restrict__ o, int n, float v)
{ const int i = blockIdx.x * 256 + threadIdx.x; if (i < n) o[i] = v; }

extern "C" void kernel_launch(void* const* d_in, const int* in_sizes, int n_in,
                              void* d_out, int out_size, void* d_ws, size_t ws_size,
                              hipStream_t stream)
{
  (void)in_sizes; (void)n_in;
  const float* X     = (const float*)d_in[0];
  const float* Wioux = (const float*)d_in[1];
  const float* bioux = (const float*)d_in[2];
  const float* Wiouh = (const float*)d_in[3];
  const float* biouh = (const float*)d_in[4];
  const float* Wlx   = (const float*)d_in[5];
  const float* blx   = (const float*)d_in[6];
  const float* Wlh   = (const float*)d_in[7];
  const float* blh   = (const float*)d_in[8];
  const float* lb    = (const float*)d_in[9];
  const int* rel_fw  = (const int*)d_in[10];
  const int* dep_fw  = (const int*)d_in[11];
  const unsigned char* mask_fw_raw = (const unsigned char*)d_in[12];
  const int* rel_bw  = (const int*)d_in[13];
  const int* dep_bw  = (const int*)d_in[14];
  const unsigned char* mask_bw_raw = (const unsigned char*)d_in[15];
  float* out = (float*)d_out;

  const int nmask = S_LEN * KREL;                  // 65536
  const size_t needP = (size_t)S_LEN * 3072 * 4;   // 96 MB
  const size_t needG = (size_t)S_LEN * 512 * 4;    // 16 MB each
  const size_t need  = 32768 + needP + 2 * needG + 2 * (size_t)nmask;
  if (ws_size < need) {
    k_fill<<<(out_size + 255) / 256, 256, 0, stream>>>(out, out_size, 12345.0f);
    return;
  }
  char* ws = (char*)d_ws;
  u64*   rec = (u64*)ws;                   // [2 buf][2 dir][512] packets
  float* P   = (float*)(ws + 32768);
  float* Gfw = (float*)(ws + 32768 + needP);
  float* Gbw = Gfw + (size_t)S_LEN * 512;
  unsigned char* Mfw = (unsigned char*)(ws + 32768 + needP + 2 * needG);
  unsigned char* Mbw = Mfw + nmask;

  hipMemsetAsync(rec, 0, 16384, stream);   // tags must start at 0 (ws poisoned 0xAA)
  k_maskcvt<<<64, 256, 0, stream>>>(mask_fw_raw, Mfw, nmask);
  k_maskcvt<<<64, 256, 0, stream>>>(mask_bw_raw, Mbw, nmask);
  dim3 gg(S_LEN / 64, 3072 / 64);
  k_gemm<<<gg, 256, 0, stream>>>(X, Wioux, Wlx, bioux, biouh, blx, blh, P);
  k_rec<<<2 * WPD, 256, 0, stream>>>(Wiouh, Wlh, P, lb, rel_fw, dep_fw, Mfw,
                                     rel_bw, dep_bw, Mbw, Gfw, Gbw, rec, out);
}